// Round 2
// baseline (9371.407 us; speedup 1.0000x reference)
//
#include <hip/hip_runtime.h>
#include <cstdint>
#include <cstddef>

// Problem constants
#define BATCH 16
#define DIM 192
#define HEADS 6
#define HD 32
#define HW 4096            // 64*64 tokens per image
#define TOK 65536          // BATCH*HW
#define QKV_D 576
#define MLP_D 768
#define CONV_K 1728        // 192*9
#define SCALE 0.17677669529663687f  // 32^-0.5

#define CH 8192            // token chunk for big intermediates
#define NCHUNK (TOK / CH)  // 8

__device__ __forceinline__ float waveSum(float v) {
#pragma unroll
  for (int off = 32; off; off >>= 1) v += __shfl_xor(v, off, 64);
  return v;
}

// ---------------- LayerNorm kernels (wave per token, 192 ch = 3/lane) -------

__global__ __launch_bounds__(256) void embed_ln_k(
    const float* __restrict__ x, const float* __restrict__ g,
    const float* __restrict__ be, float* __restrict__ y) {
  int tok = (blockIdx.x << 2) + (threadIdx.x >> 6);
  int lane = threadIdx.x & 63;
  int b = tok >> 12, t = tok & 4095;
  const float* xp = x + (((size_t)b * DIM) << 12) + t;
  float v0 = xp[(size_t)lane << 12];
  float v1 = xp[(size_t)(lane + 64) << 12];
  float v2 = xp[(size_t)(lane + 128) << 12];
  float mu = waveSum(v0 + v1 + v2) * (1.f / 192.f);
  float d0 = v0 - mu, d1 = v1 - mu, d2 = v2 - mu;
  float var = waveSum(d0 * d0 + d1 * d1 + d2 * d2) * (1.f / 192.f);
  float rs = rsqrtf(var + 1e-5f);
  float* yp = y + (size_t)tok * DIM;
  yp[lane]       = d0 * rs * g[lane]       + be[lane];
  yp[lane + 64]  = d1 * rs * g[lane + 64]  + be[lane + 64];
  yp[lane + 128] = d2 * rs * g[lane + 128] + be[lane + 128];
}

// LN1 + (optional roll -4) + window partition
__global__ __launch_bounds__(256) void ln_window_k(
    const float* __restrict__ y, const float* __restrict__ g,
    const float* __restrict__ be, float* __restrict__ xw, int shifted) {
  int m = (blockIdx.x << 2) + (threadIdx.x >> 6);
  int lane = threadIdx.x & 63;
  int widx = m >> 6, n = m & 63;
  int b = widx >> 6, win = widx & 63;
  int hp = ((win >> 3) << 3) + (n >> 3);
  int wp = ((win & 7) << 3) + (n & 7);
  if (shifted) { hp = (hp + 4) & 63; wp = (wp + 4) & 63; }
  int src = (b << 12) + (hp << 6) + wp;
  const float* yp = y + (size_t)src * DIM;
  float v0 = yp[lane], v1 = yp[lane + 64], v2 = yp[lane + 128];
  float mu = waveSum(v0 + v1 + v2) * (1.f / 192.f);
  float d0 = v0 - mu, d1 = v1 - mu, d2 = v2 - mu;
  float var = waveSum(d0 * d0 + d1 * d1 + d2 * d2) * (1.f / 192.f);
  float rs = rsqrtf(var + 1e-5f);
  float* op = xw + (size_t)m * DIM;
  op[lane]       = d0 * rs * g[lane]       + be[lane];
  op[lane + 64]  = d1 * rs * g[lane + 64]  + be[lane + 64];
  op[lane + 128] = d2 * rs * g[lane + 128] + be[lane + 128];
}

__global__ __launch_bounds__(256) void ln_plain_k(
    const float* __restrict__ y, const float* __restrict__ g,
    const float* __restrict__ be, float* __restrict__ h) {
  int tok = (blockIdx.x << 2) + (threadIdx.x >> 6);
  int lane = threadIdx.x & 63;
  const float* yp = y + (size_t)tok * DIM;
  float v0 = yp[lane], v1 = yp[lane + 64], v2 = yp[lane + 128];
  float mu = waveSum(v0 + v1 + v2) * (1.f / 192.f);
  float d0 = v0 - mu, d1 = v1 - mu, d2 = v2 - mu;
  float var = waveSum(d0 * d0 + d1 * d1 + d2 * d2) * (1.f / 192.f);
  float rs = rsqrtf(var + 1e-5f);
  float* op = h + (size_t)tok * DIM;
  op[lane]       = d0 * rs * g[lane]       + be[lane];
  op[lane + 64]  = d1 * rs * g[lane + 64]  + be[lane + 64];
  op[lane + 128] = d2 * rs * g[lane + 128] + be[lane + 128];
}

__global__ __launch_bounds__(256) void ln_tr_k(
    const float* __restrict__ y, const float* __restrict__ g,
    const float* __restrict__ be, float* __restrict__ z) {
  int tok = (blockIdx.x << 2) + (threadIdx.x >> 6);
  int lane = threadIdx.x & 63;
  int b = tok >> 12, t = tok & 4095;
  const float* yp = y + (size_t)tok * DIM;
  float v0 = yp[lane], v1 = yp[lane + 64], v2 = yp[lane + 128];
  float mu = waveSum(v0 + v1 + v2) * (1.f / 192.f);
  float d0 = v0 - mu, d1 = v1 - mu, d2 = v2 - mu;
  float var = waveSum(d0 * d0 + d1 * d1 + d2 * d2) * (1.f / 192.f);
  float rs = rsqrtf(var + 1e-5f);
  float* zp = z + (((size_t)b * DIM) << 12) + t;
  zp[(size_t)lane << 12]         = d0 * rs * g[lane]       + be[lane];
  zp[(size_t)(lane + 64) << 12]  = d1 * rs * g[lane + 64]  + be[lane + 64];
  zp[(size_t)(lane + 128) << 12] = d2 * rs * g[lane + 128] + be[lane + 128];
}

// ---------------- Windowed attention: block per (window, head) -------------
// qkv points at this CHUNK's QKV rows; out points at this chunk's output rows.
// widx0 = global window index of the chunk's first window (for mask zones).
__global__ __launch_bounds__(64) void attn_k(
    const float* __restrict__ qkv, const float* __restrict__ rpb,
    float* __restrict__ out, int shifted, int widx0) {
  __shared__ float kl[64 * 32];
  __shared__ float vl[64 * 32];
  __shared__ float rp[225];
  const int lwidx = blockIdx.x / HEADS;             // chunk-local window
  const int head = blockIdx.x - lwidx * HEADS;
  const int lane = threadIdx.x;

  for (int i = lane; i < 225; i += 64) rp[i] = rpb[i * HEADS + head];

  const float* kbase = qkv + (size_t)lwidx * 64 * QKV_D + DIM + head * HD;
  const float* vbase = kbase + DIM;
#pragma unroll
  for (int j = 0; j < 8; ++j) {
    int f4 = lane + (j << 6);
    int m = f4 >> 3;
    int d = (f4 & 7) << 2;
    float4 kv = *(const float4*)(kbase + (size_t)m * QKV_D + d);
    float4 vv = *(const float4*)(vbase + (size_t)m * QKV_D + d);
    *(float4*)&kl[(m << 5) + d] = kv;
    *(float4*)&vl[(m << 5) + d] = vv;
  }

  float qr[32];
  const float* qbase = qkv + ((size_t)(lwidx * 64 + lane)) * QKV_D + head * HD;
#pragma unroll
  for (int d = 0; d < 32; d += 4) {
    float4 q4 = *(const float4*)(qbase + d);
    qr[d]     = q4.x * SCALE;
    qr[d + 1] = q4.y * SCALE;
    qr[d + 2] = q4.z * SCALE;
    qr[d + 3] = q4.w * SCALE;
  }
  __syncthreads();

  const int rn = lane >> 3, cn = lane & 7;
  int zq = 0;
  const int win = (widx0 + lwidx) & 63;             // global window in image
  if (shifted) {
    int hq = ((win >> 3) << 3) + rn;
    int wq = ((win & 7) << 3) + cn;
    int zr = hq < 56 ? 0 : (hq < 60 ? 1 : 2);
    int zc = wq < 56 ? 0 : (wq < 60 ? 1 : 2);
    zq = zr * 3 + zc;
  }

  float p[64];
  float mx = -1e30f;
#pragma unroll
  for (int m = 0; m < 64; ++m) {
    float s = 0.f;
    const float4* kr = (const float4*)&kl[m << 5];
#pragma unroll
    for (int d4 = 0; d4 < 8; ++d4) {
      float4 k4 = kr[d4];
      int d = d4 << 2;
      s = fmaf(qr[d], k4.x, s);
      s = fmaf(qr[d + 1], k4.y, s);
      s = fmaf(qr[d + 2], k4.z, s);
      s = fmaf(qr[d + 3], k4.w, s);
    }
    int rm = m >> 3, cm = m & 7;
    s += rp[(rn - rm + 7) * 15 + (cn - cm + 7)];
    if (shifted) {
      int hm = ((win >> 3) << 3) + rm;
      int wm = ((win & 7) << 3) + cm;
      int zr = hm < 56 ? 0 : (hm < 60 ? 1 : 2);
      int zc = wm < 56 ? 0 : (wm < 60 ? 1 : 2);
      if (zr * 3 + zc != zq) s -= 100.f;
    }
    p[m] = s;
    mx = fmaxf(mx, s);
  }
  float sum = 0.f;
#pragma unroll
  for (int m = 0; m < 64; ++m) { p[m] = __expf(p[m] - mx); sum += p[m]; }
  float inv = 1.f / sum;

  float o[32];
#pragma unroll
  for (int d = 0; d < 32; ++d) o[d] = 0.f;
#pragma unroll
  for (int m = 0; m < 64; ++m) {
    float pm = p[m] * inv;
    const float4* vr = (const float4*)&vl[m << 5];
#pragma unroll
    for (int d4 = 0; d4 < 8; ++d4) {
      float4 v4 = vr[d4];
      int d = d4 << 2;
      o[d]     = fmaf(pm, v4.x, o[d]);
      o[d + 1] = fmaf(pm, v4.y, o[d + 1]);
      o[d + 2] = fmaf(pm, v4.z, o[d + 2]);
      o[d + 3] = fmaf(pm, v4.w, o[d + 3]);
    }
  }
  float* ob = out + ((size_t)(lwidx * 64 + lane)) * DIM + head * HD;
#pragma unroll
  for (int d = 0; d < 32; d += 4) {
    float4 t{o[d], o[d + 1], o[d + 2], o[d + 3]};
    *(float4*)(ob + d) = t;
  }
}

// ---------------- Tiled fp32 GEMM: C[M,N] = A[M,K] @ W[N,K]^T (+epilogue) ---
// Rows are LOCAL to the provided A/C pointers (chunked launches pre-offset).
// EPI 0: C = acc+bias           (QKV)
// EPI 1: C = gelu(acc+bias)     (FC1)
// EPI 2: C += acc+bias          (FC2 residual into y rows)
// EPI 3: scatter: y[winrev+roll] += acc+bias   (proj; launched full-size)
// EPI 4: out[NCHW] = acc + Z[NCHW]             (conv, IM2COL A-gather)
template <int EPI, bool IM2COL>
__global__ __launch_bounds__(256) void gemm_k(
    const float* __restrict__ A, const float* __restrict__ W,
    const float* __restrict__ bias, float* __restrict__ C,
    const float* __restrict__ Z, int N, int K, int shifted) {
  __shared__ float As[16][68];
  __shared__ float Bs[16][68];
  const int tid = threadIdx.x;
  const int tx = tid & 15, ty = tid >> 4;
  const int row0 = blockIdx.y << 6;
  const int col0 = blockIdx.x << 6;
  float acc[4][4] = {};

  for (int k0 = 0; k0 < K; k0 += 16) {
#pragma unroll
    for (int i = 0; i < 4; ++i) {
      int idx = tid + (i << 8);
      int r = idx >> 4, kk = idx & 15;
      float av;
      if (IM2COL) {
        int m = row0 + r;
        int k = k0 + kk;
        int b = m >> 12, hw = m & 4095;
        int h = hw >> 6, w = hw & 63;
        int ci = k / 9;
        int k9 = k - ci * 9;
        int kh = k9 / 3, kw = k9 - kh * 3;
        int ih = h + kh - 1, iw = w + kw - 1;
        av = (ih >= 0 && ih < 64 && iw >= 0 && iw < 64)
                 ? A[(((size_t)(b * DIM + ci)) << 12) + (ih << 6) + iw]
                 : 0.f;
      } else {
        av = A[(size_t)(row0 + r) * K + k0 + kk];
      }
      As[kk][r] = av;
      Bs[kk][r] = W[(size_t)(col0 + r) * K + k0 + kk];
    }
    __syncthreads();
#pragma unroll
    for (int kk = 0; kk < 16; ++kk) {
      float4 a4 = *(const float4*)&As[kk][ty << 2];
      float4 b4 = *(const float4*)&Bs[kk][tx << 2];
      float a[4] = {a4.x, a4.y, a4.z, a4.w};
      float b[4] = {b4.x, b4.y, b4.z, b4.w};
#pragma unroll
      for (int i = 0; i < 4; ++i)
#pragma unroll
        for (int j = 0; j < 4; ++j) acc[i][j] = fmaf(a[i], b[j], acc[i][j]);
    }
    __syncthreads();
  }

#pragma unroll
  for (int i = 0; i < 4; ++i) {
    int row = row0 + (ty << 2) + i;
#pragma unroll
    for (int j = 0; j < 4; ++j) {
      int col = col0 + (tx << 2) + j;
      float v = acc[i][j];
      if (EPI == 0) {
        C[(size_t)row * N + col] = v + bias[col];
      } else if (EPI == 1) {
        float xg = v + bias[col];
        C[(size_t)row * N + col] =
            0.5f * xg * (1.f + erff(xg * 0.7071067811865475f));
      } else if (EPI == 2) {
        C[(size_t)row * N + col] += v + bias[col];
      } else if (EPI == 3) {
        int widx = row >> 6, n = row & 63;
        int b = widx >> 6, win = widx & 63;
        int hp = ((win >> 3) << 3) + (n >> 3);
        int wp = ((win & 7) << 3) + (n & 7);
        if (shifted) { hp = (hp + 4) & 63; wp = (wp + 4) & 63; }
        int dst = (b << 12) + (hp << 6) + wp;
        C[(size_t)dst * DIM + col] += v + bias[col];
      } else {  // EPI 4
        int b = row >> 12, hw = row & 4095;
        size_t o = (((size_t)(b * DIM + col)) << 12) + hw;
        C[o] = v + Z[o];
      }
    }
  }
}

// ---------------------------------------------------------------------------
extern "C" void kernel_launch(void* const* d_in, const int* in_sizes, int n_in,
                              void* d_out, int out_size, void* d_ws,
                              size_t ws_size, hipStream_t stream) {
  const float* x      = (const float*)d_in[0];
  const float* en_g   = (const float*)d_in[1];
  const float* en_b   = (const float*)d_in[2];
  const float* n1_g   = (const float*)d_in[3];
  const float* n1_b   = (const float*)d_in[4];
  const float* qkv_w  = (const float*)d_in[5];
  const float* qkv_b  = (const float*)d_in[6];
  const float* proj_w = (const float*)d_in[7];
  const float* proj_b = (const float*)d_in[8];
  const float* rpb    = (const float*)d_in[9];
  const float* n2_g   = (const float*)d_in[10];
  const float* n2_b   = (const float*)d_in[11];
  const float* fc1_w  = (const float*)d_in[12];
  const float* fc1_b  = (const float*)d_in[13];
  const float* fc2_w  = (const float*)d_in[14];
  const float* fc2_b  = (const float*)d_in[15];
  const float* fn_g   = (const float*)d_in[16];
  const float* fn_b   = (const float*)d_in[17];
  const float* conv_w = (const float*)d_in[18];
  float* out = (float*)d_out;

  // workspace: y (50.3MB) | buf1 (50.3MB) | buf2 (25.2MB chunk) = 125.8MB
  float* y    = (float*)d_ws;
  float* buf1 = (float*)((char*)d_ws + 50331648);
  float* buf2 = (float*)((char*)d_ws + 100663296);

  embed_ln_k<<<16384, 256, 0, stream>>>(x, en_g, en_b, y);

  for (int i = 0; i < 6; ++i) {
    int sh = i & 1;
    // LN1 + shift + window partition (full size) -> buf1
    ln_window_k<<<16384, 256, 0, stream>>>(y, n1_g + i * DIM, n1_b + i * DIM,
                                           buf1, sh);
    // QKV + attention, chunked over tokens (windows contiguous in buf1)
    for (int c = 0; c < NCHUNK; ++c) {
      const float* Ac = buf1 + (size_t)c * CH * DIM;
      gemm_k<0, false><<<dim3(9, CH / 64), 256, 0, stream>>>(
          Ac, qkv_w + (size_t)i * QKV_D * DIM, qkv_b + i * QKV_D, buf2, nullptr,
          QKV_D, DIM, 0);
      attn_k<<<(CH / 64) * HEADS, 64, 0, stream>>>(
          buf2, rpb + i * 225 * HEADS, buf1 + (size_t)c * CH * DIM, sh,
          c * (CH / 64));
    }
    // proj + window-reverse + roll scatter into residual y (full size)
    gemm_k<3, false><<<dim3(3, 1024), 256, 0, stream>>>(
        buf1, proj_w + (size_t)i * DIM * DIM, proj_b + i * DIM, y, nullptr, DIM,
        DIM, sh);
    // LN2 (full size) -> buf1
    ln_plain_k<<<16384, 256, 0, stream>>>(y, n2_g + i * DIM, n2_b + i * DIM,
                                          buf1);
    // MLP, chunked
    for (int c = 0; c < NCHUNK; ++c) {
      const float* Ac = buf1 + (size_t)c * CH * DIM;
      gemm_k<1, false><<<dim3(12, CH / 64), 256, 0, stream>>>(
          Ac, fc1_w + (size_t)i * MLP_D * DIM, fc1_b + i * MLP_D, buf2, nullptr,
          MLP_D, DIM, 0);
      gemm_k<2, false><<<dim3(3, CH / 64), 256, 0, stream>>>(
          buf2, fc2_w + (size_t)i * DIM * MLP_D, fc2_b + i * DIM,
          y + (size_t)c * CH * DIM, nullptr, DIM, MLP_D, 0);
    }
  }

  ln_tr_k<<<16384, 256, 0, stream>>>(y, fn_g, fn_b, buf1);
  gemm_k<4, true><<<dim3(3, 1024), 256, 0, stream>>>(
      buf1, conv_w, nullptr, out, buf1, DIM, CONV_K, 0);
}

// Round 3
// 3175.690 us; speedup vs baseline: 2.9510x; 2.9510x over previous
//
#include <hip/hip_runtime.h>
#include <cstdint>
#include <cstddef>

// Problem constants
#define BATCH 16
#define DIM 192
#define HEADS 6
#define HD 32
#define HW 4096
#define TOK 65536
#define QKV_D 576
#define MLP_D 768
#define CONV_K 1728
#define SCALE 0.17677669529663687f  // 32^-0.5

#define CH 16384
#define NCHUNK 4

typedef __bf16 bf16x8 __attribute__((ext_vector_type(8)));
typedef float f32x4 __attribute__((ext_vector_type(4)));

__device__ __forceinline__ unsigned short f2bf(float f) {
  union { float f; unsigned u; } c;
  c.f = f;
  return (unsigned short)((c.u + 0x7fffu + ((c.u >> 16) & 1)) >> 16);
}

__device__ __forceinline__ float waveSum(float v) {
#pragma unroll
  for (int off = 32; off; off >>= 1) v += __shfl_xor(v, off, 64);
  return v;
}

// global -> LDS direct (16B/lane). LDS dest must be wave-uniform base.
#define GLD(SRC, DST)                                                     \
  __builtin_amdgcn_global_load_lds(                                       \
      (const __attribute__((address_space(1))) void*)(SRC),               \
      (__attribute__((address_space(3))) void*)(DST), 16, 0, 0)

// ---------------- weight fp32 -> bf16 convert ------------------------------
__global__ __launch_bounds__(256) void cvt_k(const float* __restrict__ s,
                                             unsigned short* __restrict__ d,
                                             int n) {
  int i = ((blockIdx.x << 8) + threadIdx.x) << 2;
  if (i < n) {
    float4 v = *(const float4*)(s + i);
    d[i] = f2bf(v.x);
    d[i + 1] = f2bf(v.y);
    d[i + 2] = f2bf(v.z);
    d[i + 3] = f2bf(v.w);
  }
}

// ---------------- LayerNorm kernels (wave per token, 192 ch = 3/lane) -------

__global__ __launch_bounds__(256) void embed_ln_k(
    const float* __restrict__ x, const float* __restrict__ g,
    const float* __restrict__ be, float* __restrict__ y) {
  int tok = (blockIdx.x << 2) + (threadIdx.x >> 6);
  int lane = threadIdx.x & 63;
  int b = tok >> 12, t = tok & 4095;
  const float* xp = x + (((size_t)b * DIM) << 12) + t;
  float v0 = xp[(size_t)lane << 12];
  float v1 = xp[(size_t)(lane + 64) << 12];
  float v2 = xp[(size_t)(lane + 128) << 12];
  float mu = waveSum(v0 + v1 + v2) * (1.f / 192.f);
  float d0 = v0 - mu, d1 = v1 - mu, d2 = v2 - mu;
  float var = waveSum(d0 * d0 + d1 * d1 + d2 * d2) * (1.f / 192.f);
  float rs = rsqrtf(var + 1e-5f);
  float* yp = y + (size_t)tok * DIM;
  yp[lane] = d0 * rs * g[lane] + be[lane];
  yp[lane + 64] = d1 * rs * g[lane + 64] + be[lane + 64];
  yp[lane + 128] = d2 * rs * g[lane + 128] + be[lane + 128];
}

// LN1 + (optional roll -4) + window partition -> bf16
__global__ __launch_bounds__(256) void ln_window_k(
    const float* __restrict__ y, const float* __restrict__ g,
    const float* __restrict__ be, unsigned short* __restrict__ xw,
    int shifted) {
  int m = (blockIdx.x << 2) + (threadIdx.x >> 6);
  int lane = threadIdx.x & 63;
  int widx = m >> 6, n = m & 63;
  int b = widx >> 6, win = widx & 63;
  int hp = ((win >> 3) << 3) + (n >> 3);
  int wp = ((win & 7) << 3) + (n & 7);
  if (shifted) { hp = (hp + 4) & 63; wp = (wp + 4) & 63; }
  int src = (b << 12) + (hp << 6) + wp;
  const float* yp = y + (size_t)src * DIM;
  float v0 = yp[lane], v1 = yp[lane + 64], v2 = yp[lane + 128];
  float mu = waveSum(v0 + v1 + v2) * (1.f / 192.f);
  float d0 = v0 - mu, d1 = v1 - mu, d2 = v2 - mu;
  float var = waveSum(d0 * d0 + d1 * d1 + d2 * d2) * (1.f / 192.f);
  float rs = rsqrtf(var + 1e-5f);
  unsigned short* op = xw + (size_t)m * DIM;
  op[lane] = f2bf(d0 * rs * g[lane] + be[lane]);
  op[lane + 64] = f2bf(d1 * rs * g[lane + 64] + be[lane + 64]);
  op[lane + 128] = f2bf(d2 * rs * g[lane + 128] + be[lane + 128]);
}

// LN2 -> bf16
__global__ __launch_bounds__(256) void ln_plain_k(
    const float* __restrict__ y, const float* __restrict__ g,
    const float* __restrict__ be, unsigned short* __restrict__ h) {
  int tok = (blockIdx.x << 2) + (threadIdx.x >> 6);
  int lane = threadIdx.x & 63;
  const float* yp = y + (size_t)tok * DIM;
  float v0 = yp[lane], v1 = yp[lane + 64], v2 = yp[lane + 128];
  float mu = waveSum(v0 + v1 + v2) * (1.f / 192.f);
  float d0 = v0 - mu, d1 = v1 - mu, d2 = v2 - mu;
  float var = waveSum(d0 * d0 + d1 * d1 + d2 * d2) * (1.f / 192.f);
  float rs = rsqrtf(var + 1e-5f);
  unsigned short* op = h + (size_t)tok * DIM;
  op[lane] = f2bf(d0 * rs * g[lane] + be[lane]);
  op[lane + 64] = f2bf(d1 * rs * g[lane + 64] + be[lane + 64]);
  op[lane + 128] = f2bf(d2 * rs * g[lane + 128] + be[lane + 128]);
}

// final LN + transpose to NCHW fp32 (zbuf)
__global__ __launch_bounds__(256) void ln_tr_k(
    const float* __restrict__ y, const float* __restrict__ g,
    const float* __restrict__ be, float* __restrict__ z) {
  int tok = (blockIdx.x << 2) + (threadIdx.x >> 6);
  int lane = threadIdx.x & 63;
  int b = tok >> 12, t = tok & 4095;
  const float* yp = y + (size_t)tok * DIM;
  float v0 = yp[lane], v1 = yp[lane + 64], v2 = yp[lane + 128];
  float mu = waveSum(v0 + v1 + v2) * (1.f / 192.f);
  float d0 = v0 - mu, d1 = v1 - mu, d2 = v2 - mu;
  float var = waveSum(d0 * d0 + d1 * d1 + d2 * d2) * (1.f / 192.f);
  float rs = rsqrtf(var + 1e-5f);
  float* zp = z + (((size_t)b * DIM) << 12) + t;
  zp[(size_t)lane << 12] = d0 * rs * g[lane] + be[lane];
  zp[(size_t)(lane + 64) << 12] = d1 * rs * g[lane + 64] + be[lane + 64];
  zp[(size_t)(lane + 128) << 12] = d2 * rs * g[lane + 128] + be[lane + 128];
}

// ---------------- Windowed attention (fp32 in, bf16 out) -------------------
__global__ __launch_bounds__(64) void attn_k(
    const float* __restrict__ qkv, const float* __restrict__ rpb,
    unsigned short* __restrict__ out, int shifted, int widx0) {
  __shared__ float kl[64 * 32];
  __shared__ float vl[64 * 32];
  __shared__ float rp[225];
  const int lwidx = blockIdx.x / HEADS;
  const int head = blockIdx.x - lwidx * HEADS;
  const int lane = threadIdx.x;

  for (int i = lane; i < 225; i += 64) rp[i] = rpb[i * HEADS + head];

  const float* kbase = qkv + (size_t)lwidx * 64 * QKV_D + DIM + head * HD;
  const float* vbase = kbase + DIM;
#pragma unroll
  for (int j = 0; j < 8; ++j) {
    int f4 = lane + (j << 6);
    int m = f4 >> 3;
    int d = (f4 & 7) << 2;
    float4 kv = *(const float4*)(kbase + (size_t)m * QKV_D + d);
    float4 vv = *(const float4*)(vbase + (size_t)m * QKV_D + d);
    *(float4*)&kl[(m << 5) + d] = kv;
    *(float4*)&vl[(m << 5) + d] = vv;
  }

  float qr[32];
  const float* qbase = qkv + ((size_t)(lwidx * 64 + lane)) * QKV_D + head * HD;
#pragma unroll
  for (int d = 0; d < 32; d += 4) {
    float4 q4 = *(const float4*)(qbase + d);
    qr[d] = q4.x * SCALE;
    qr[d + 1] = q4.y * SCALE;
    qr[d + 2] = q4.z * SCALE;
    qr[d + 3] = q4.w * SCALE;
  }
  __syncthreads();

  const int rn = lane >> 3, cn = lane & 7;
  int zq = 0;
  const int win = (widx0 + lwidx) & 63;
  if (shifted) {
    int hq = ((win >> 3) << 3) + rn;
    int wq = ((win & 7) << 3) + cn;
    int zr = hq < 56 ? 0 : (hq < 60 ? 1 : 2);
    int zc = wq < 56 ? 0 : (wq < 60 ? 1 : 2);
    zq = zr * 3 + zc;
  }

  float p[64];
  float mx = -1e30f;
#pragma unroll
  for (int m = 0; m < 64; ++m) {
    float s = 0.f;
    const float4* kr = (const float4*)&kl[m << 5];
#pragma unroll
    for (int d4 = 0; d4 < 8; ++d4) {
      float4 k4 = kr[d4];
      int d = d4 << 2;
      s = fmaf(qr[d], k4.x, s);
      s = fmaf(qr[d + 1], k4.y, s);
      s = fmaf(qr[d + 2], k4.z, s);
      s = fmaf(qr[d + 3], k4.w, s);
    }
    int rm = m >> 3, cm = m & 7;
    s += rp[(rn - rm + 7) * 15 + (cn - cm + 7)];
    if (shifted) {
      int hm = ((win >> 3) << 3) + rm;
      int wm = ((win & 7) << 3) + cm;
      int zr = hm < 56 ? 0 : (hm < 60 ? 1 : 2);
      int zc = wm < 56 ? 0 : (wm < 60 ? 1 : 2);
      if (zr * 3 + zc != zq) s -= 100.f;
    }
    p[m] = s;
    mx = fmaxf(mx, s);
  }
  float sum = 0.f;
#pragma unroll
  for (int m = 0; m < 64; ++m) {
    p[m] = __expf(p[m] - mx);
    sum += p[m];
  }
  float inv = 1.f / sum;

  float o[32];
#pragma unroll
  for (int d = 0; d < 32; ++d) o[d] = 0.f;
#pragma unroll
  for (int m = 0; m < 64; ++m) {
    float pm = p[m] * inv;
    const float4* vr = (const float4*)&vl[m << 5];
#pragma unroll
    for (int d4 = 0; d4 < 8; ++d4) {
      float4 v4 = vr[d4];
      int d = d4 << 2;
      o[d] = fmaf(pm, v4.x, o[d]);
      o[d + 1] = fmaf(pm, v4.y, o[d + 1]);
      o[d + 2] = fmaf(pm, v4.z, o[d + 2]);
      o[d + 3] = fmaf(pm, v4.w, o[d + 3]);
    }
  }
  unsigned short* ob = out + ((size_t)(lwidx * 64 + lane)) * DIM + head * HD;
#pragma unroll
  for (int c = 0; c < 4; ++c) {
    uint4 t;
    t.x = (unsigned)f2bf(o[c * 8 + 0]) | ((unsigned)f2bf(o[c * 8 + 1]) << 16);
    t.y = (unsigned)f2bf(o[c * 8 + 2]) | ((unsigned)f2bf(o[c * 8 + 3]) << 16);
    t.z = (unsigned)f2bf(o[c * 8 + 4]) | ((unsigned)f2bf(o[c * 8 + 5]) << 16);
    t.w = (unsigned)f2bf(o[c * 8 + 6]) | ((unsigned)f2bf(o[c * 8 + 7]) << 16);
    *(uint4*)(ob + c * 8) = t;
  }
}

// ---------------- MFMA bf16 GEMM: C[M,N] = A[M,K] @ W[N,K]^T + epilogue ----
// 128x64 tile, BK=64, 4 waves (each 32 rows x 64 cols = 2x4 16x16 frags).
// LDS layout XOR-swizzled (16B slot ^= row&7) via pre-swizzled global source
// (global_load_lds writes linearly) to kill the stride-128B bank conflict.
// EPI 0: C(fp32) = acc+bias                 (QKV)
// EPI 1: C(bf16) = gelu(acc+bias)           (FC1)
// EPI 2: C(fp32) += acc+bias                (FC2 residual into y chunk)
// EPI 3: y[winrev+roll] += acc+bias         (proj scatter, full-size)
// EPI 4: C(fp32)[NCHW] = acc + Z[NCHW]      (conv; im2col gather from Z)
template <int EPI, bool IM2COL>
__global__ __launch_bounds__(256) void mgemm_k(
    const unsigned short* __restrict__ A, const unsigned short* __restrict__ W,
    const float* __restrict__ bias, void* __restrict__ Cv,
    const float* __restrict__ Z, int N, int K, int shifted) {
  __shared__ unsigned short As[128 * 64];
  __shared__ unsigned short Bs[64 * 64];
  const int tid = threadIdx.x;
  const int w = tid >> 6, lane = tid & 63;
  const int row0 = blockIdx.y << 7;
  const int col0 = blockIdx.x << 6;
  f32x4 acc[2][4] = {};

  for (int k0 = 0; k0 < K; k0 += 64) {
    if (k0) __syncthreads();
    // ---- stage B: 64 rows x 64 k bf16 = 512 x16B chunks, 2 rounds
#pragma unroll
    for (int r = 0; r < 2; ++r) {
      int q = (r << 8) + tid;
      int brow = q >> 3, cs = q & 7;
      int kg = cs ^ (brow & 7);  // pre-swizzled source k-group
      GLD(W + (size_t)(col0 + brow) * K + k0 + (kg << 3),
          Bs + (((r << 8) + (w << 6)) << 3));
    }
    if (!IM2COL) {
      // ---- stage A: 128 rows x 64 k = 1024 chunks, 4 rounds
#pragma unroll
      for (int r = 0; r < 4; ++r) {
        int q = (r << 8) + tid;
        int arow = q >> 3, cs = q & 7;
        int kg = cs ^ (arow & 7);
        GLD(A + (size_t)(row0 + arow) * K + k0 + (kg << 3),
            As + (((r << 8) + (w << 6)) << 3));
      }
    } else {
      // ---- im2col gather from Z (fp32 NCHW), convert, swizzled ds_write
      for (int i = tid; i < 8192; i += 256) {
        int arow = i >> 6, kk2 = i & 63;
        int m = row0 + arow;
        int k = k0 + kk2;
        int b = m >> 12, hw_ = m & 4095;
        int h = hw_ >> 6, ww = hw_ & 63;
        int ci = k / 9, k9 = k - ci * 9;
        int kh = k9 / 3, kw = k9 - kh * 3;
        int ih = h + kh - 1, iw = ww + kw - 1;
        float av = (ih >= 0 && ih < 64 && iw >= 0 && iw < 64)
                       ? Z[(((size_t)(b * DIM + ci)) << 12) + (ih << 6) + iw]
                       : 0.f;
        As[(arow << 6) + (((kk2 >> 3) ^ (arow & 7)) << 3) + (kk2 & 7)] =
            f2bf(av);
      }
    }
    __syncthreads();

    const int frow = lane & 15;
    const int fk = (lane >> 4) << 3;
#pragma unroll
    for (int kk = 0; kk < 64; kk += 32) {
      int slotk = (kk + fk) >> 3;
      int ar0 = (w << 5) + frow, ar1 = ar0 + 16;
      bf16x8 a0 = *(const bf16x8*)&As[(ar0 << 6) + ((slotk ^ (ar0 & 7)) << 3)];
      bf16x8 a1 = *(const bf16x8*)&As[(ar1 << 6) + ((slotk ^ (ar1 & 7)) << 3)];
      int bs = (slotk ^ (frow & 7)) << 3;
      bf16x8 b0 = *(const bf16x8*)&Bs[(frow << 6) + bs];
      bf16x8 b1 = *(const bf16x8*)&Bs[((frow + 16) << 6) + bs];
      bf16x8 b2 = *(const bf16x8*)&Bs[((frow + 32) << 6) + bs];
      bf16x8 b3 = *(const bf16x8*)&Bs[((frow + 48) << 6) + bs];
      acc[0][0] = __builtin_amdgcn_mfma_f32_16x16x32_bf16(a0, b0, acc[0][0], 0, 0, 0);
      acc[0][1] = __builtin_amdgcn_mfma_f32_16x16x32_bf16(a0, b1, acc[0][1], 0, 0, 0);
      acc[0][2] = __builtin_amdgcn_mfma_f32_16x16x32_bf16(a0, b2, acc[0][2], 0, 0, 0);
      acc[0][3] = __builtin_amdgcn_mfma_f32_16x16x32_bf16(a0, b3, acc[0][3], 0, 0, 0);
      acc[1][0] = __builtin_amdgcn_mfma_f32_16x16x32_bf16(a1, b0, acc[1][0], 0, 0, 0);
      acc[1][1] = __builtin_amdgcn_mfma_f32_16x16x32_bf16(a1, b1, acc[1][1], 0, 0, 0);
      acc[1][2] = __builtin_amdgcn_mfma_f32_16x16x32_bf16(a1, b2, acc[1][2], 0, 0, 0);
      acc[1][3] = __builtin_amdgcn_mfma_f32_16x16x32_bf16(a1, b3, acc[1][3], 0, 0, 0);
    }
  }

  // ---- epilogue: lane l, reg j -> row=(l>>4)*4+j, col=l&15 (m89 layout)
  const int erow = (lane >> 4) << 2;
  const int ecol = lane & 15;
#pragma unroll
  for (int mr = 0; mr < 2; ++mr)
#pragma unroll
    for (int nr = 0; nr < 4; ++nr)
#pragma unroll
      for (int j = 0; j < 4; ++j) {
        int row = row0 + (w << 5) + (mr << 4) + erow + j;
        int col = col0 + (nr << 4) + ecol;
        float v = acc[mr][nr][j];
        if (EPI == 0) {
          ((float*)Cv)[(size_t)row * N + col] = v + bias[col];
        } else if (EPI == 1) {
          float xg = v + bias[col];
          ((unsigned short*)Cv)[(size_t)row * N + col] =
              f2bf(0.5f * xg * (1.f + erff(xg * 0.7071067811865475f)));
        } else if (EPI == 2) {
          ((float*)Cv)[(size_t)row * N + col] += v + bias[col];
        } else if (EPI == 3) {
          int widx = row >> 6, n = row & 63;
          int b = widx >> 6, win = widx & 63;
          int hp = ((win >> 3) << 3) + (n >> 3);
          int wp = ((win & 7) << 3) + (n & 7);
          if (shifted) { hp = (hp + 4) & 63; wp = (wp + 4) & 63; }
          int dst = (b << 12) + (hp << 6) + wp;
          ((float*)Cv)[(size_t)dst * DIM + col] += v + bias[col];
        } else {
          int b = row >> 12, hw_ = row & 4095;
          size_t o = (((size_t)(b * DIM + col)) << 12) + hw_;
          ((float*)Cv)[o] = v + Z[o];
        }
      }
}

// ---------------------------------------------------------------------------
extern "C" void kernel_launch(void* const* d_in, const int* in_sizes, int n_in,
                              void* d_out, int out_size, void* d_ws,
                              size_t ws_size, hipStream_t stream) {
  const float* x = (const float*)d_in[0];
  const float* en_g = (const float*)d_in[1];
  const float* en_b = (const float*)d_in[2];
  const float* n1_g = (const float*)d_in[3];
  const float* n1_b = (const float*)d_in[4];
  const float* qkv_w = (const float*)d_in[5];
  const float* qkv_b = (const float*)d_in[6];
  const float* proj_w = (const float*)d_in[7];
  const float* proj_b = (const float*)d_in[8];
  const float* rpb = (const float*)d_in[9];
  const float* n2_g = (const float*)d_in[10];
  const float* n2_b = (const float*)d_in[11];
  const float* fc1_w = (const float*)d_in[12];
  const float* fc1_b = (const float*)d_in[13];
  const float* fc2_w = (const float*)d_in[14];
  const float* fc2_b = (const float*)d_in[15];
  const float* fn_g = (const float*)d_in[16];
  const float* fn_b = (const float*)d_in[17];
  const float* conv_w = (const float*)d_in[18];
  float* out = (float*)d_out;

  // workspace layout (bytes):
  //   y     @ 0          fp32 [65536,192]            50331648
  //   buf1  @ 50331648   bf16 [65536,192]            25165824
  //   buf2  @ 75497472   fp32 [16384,576] / bf16 FC1 37748736
  //   wbuf  @ 113246208  bf16 weights                 5971968   -> 119.2 MB
  //   zbuf  = buf1 region reinterpreted fp32 [16,192,4096] (50.3MB, end only)
  float* y = (float*)d_ws;
  unsigned short* buf1 = (unsigned short*)((char*)d_ws + 50331648);
  float* buf2f = (float*)((char*)d_ws + 75497472);
  unsigned short* buf2u = (unsigned short*)buf2f;
  unsigned short* wbuf = (unsigned short*)((char*)d_ws + 113246208);
  float* zbuf = (float*)buf1;

  unsigned short* qkv_wb = wbuf;                  // 6*576*192  = 663552
  unsigned short* proj_wb = wbuf + 663552;        // 6*192*192  = 221184
  unsigned short* fc1_wb = wbuf + 884736;         // 6*768*192  = 884736
  unsigned short* fc2_wb = wbuf + 1769472;        // 6*192*768  = 884736
  unsigned short* conv_wb = wbuf + 2654208;       // 192*1728   = 331776

  cvt_k<<<648, 256, 0, stream>>>(qkv_w, qkv_wb, 663552);
  cvt_k<<<216, 256, 0, stream>>>(proj_w, proj_wb, 221184);
  cvt_k<<<864, 256, 0, stream>>>(fc1_w, fc1_wb, 884736);
  cvt_k<<<864, 256, 0, stream>>>(fc2_w, fc2_wb, 884736);
  cvt_k<<<324, 256, 0, stream>>>(conv_w, conv_wb, 331776);

  embed_ln_k<<<16384, 256, 0, stream>>>(x, en_g, en_b, y);

  for (int i = 0; i < 6; ++i) {
    int sh = i & 1;
    ln_window_k<<<16384, 256, 0, stream>>>(y, n1_g + i * DIM, n1_b + i * DIM,
                                           buf1, sh);
    for (int c = 0; c < NCHUNK; ++c) {
      const unsigned short* Ac = buf1 + (size_t)c * CH * DIM;
      mgemm_k<0, false><<<dim3(9, CH / 128), 256, 0, stream>>>(
          Ac, qkv_wb + (size_t)i * QKV_D * DIM, qkv_b + i * QKV_D, buf2f,
          nullptr, QKV_D, DIM, 0);
      attn_k<<<(CH / 64) * HEADS, 64, 0, stream>>>(
          buf2f, rpb + i * 225 * HEADS, buf1 + (size_t)c * CH * DIM, sh,
          c * (CH / 64));
    }
    mgemm_k<3, false><<<dim3(3, TOK / 128), 256, 0, stream>>>(
        buf1, proj_wb + (size_t)i * DIM * DIM, proj_b + i * DIM, y, nullptr,
        DIM, DIM, sh);
    ln_plain_k<<<16384, 256, 0, stream>>>(y, n2_g + i * DIM, n2_b + i * DIM,
                                          buf1);
    for (int c = 0; c < NCHUNK; ++c) {
      const unsigned short* Ac = buf1 + (size_t)c * CH * DIM;
      mgemm_k<1, false><<<dim3(12, CH / 128), 256, 0, stream>>>(
          Ac, fc1_wb + (size_t)i * MLP_D * DIM, fc1_b + i * MLP_D, buf2u,
          nullptr, MLP_D, DIM, 0);
      mgemm_k<2, false><<<dim3(3, CH / 128), 256, 0, stream>>>(
          buf2u, fc2_wb + (size_t)i * DIM * MLP_D, fc2_b + i * DIM,
          y + (size_t)c * CH * DIM, nullptr, DIM, MLP_D, 0);
    }
  }

  ln_tr_k<<<16384, 256, 0, stream>>>(y, fn_g, fn_b, zbuf);
  mgemm_k<4, true><<<dim3(3, TOK / 128), 256, 0, stream>>>(
      buf1, conv_wb, nullptr, out, zbuf, DIM, CONV_K, 0);
}